// Round 4
// baseline (402.723 us; speedup 1.0000x reference)
//
#include <hip/hip_runtime.h>

#define N_Q 4096
#define N_O 4096
#define LAT 64
#define HEADS 4
#define HD 16
#define NCHUNK 16
#define OCHUNK 256
#define L2E 1.4426950408889634f

typedef float f2 __attribute__((ext_vector_type(2)));
typedef float f4 __attribute__((ext_vector_type(4)));

// ---- forced VOP3P packed fp32 ----
#define PK_FMA(acc, a, b) \
    asm("v_pk_fma_f32 %0, %1, %2, %0" : "+v"(acc) : "v"(a), "v"(b))
// broadcast LOW half of a to both lanes of the product
#define PK_FMA_LO(acc, a, b) \
    asm("v_pk_fma_f32 %0, %1, %2, %0 op_sel:[0,0,0] op_sel_hi:[0,1,1]" \
        : "+v"(acc) : "v"(a), "v"(b))
// broadcast HIGH half of a
#define PK_FMA_HI(acc, a, b) \
    asm("v_pk_fma_f32 %0, %1, %2, %0 op_sel:[1,0,0] op_sel_hi:[1,1,1]" \
        : "+v"(acc) : "v"(a), "v"(b))
__device__ __forceinline__ f2 pk_add2(f2 a, f2 b) {
    f2 d; asm("v_pk_add_f32 %0, %1, %2" : "=v"(d) : "v"(a), "v"(b)); return d;
}
__device__ __forceinline__ f2 pk_mul2(f2 a, f2 b) {
    f2 d; asm("v_pk_mul_f32 %0, %1, %2" : "=v"(d) : "v"(a), "v"(b)); return d;
}
// acc = acc*s + a*b   (s broadcast from low half of sp)
#define PK_SCALE_FMA(acc, sp, a, b) do { \
    f2 _t = pk_mul2(a, b); \
    asm("v_pk_fma_f32 %0, %1, %0, %2 op_sel:[0,0,0] op_sel_hi:[0,1,1]" \
        : "+v"(acc) : "v"(sp), "v"(_t)); } while (0)

// ---- fused prep: qc[q][j], oc[o][j], v[o][hd] ----
__global__ __launch_bounds__(256) void prep_all(
    const float* __restrict__ h_obs, const float* __restrict__ pos_obs,
    const float* __restrict__ pos_query,
    const float* __restrict__ W1, const float* __restrict__ b1,
    const float* __restrict__ Wv, const float* __restrict__ bv,
    float* __restrict__ qc, float* __restrict__ oc, float* __restrict__ vv)
{
    int gid = blockIdx.x * 256 + threadIdx.x;
    int row = gid >> 6, j = gid & 63;
    if (row < N_Q) {
        const float* pq = pos_query + row * 3;
        float acc = b1[j];
        #pragma unroll
        for (int p = 0; p < 3; ++p)
            acc = fmaf(pq[p], W1[p * LAT + j] + W1[(3 + p) * LAT + j], acc);
        qc[row * LAT + j] = acc;
    } else if (row < N_Q + N_O) {
        int o = row - N_Q;
        const float* po = pos_obs + o * 3;
        float acc = 0.f;
        #pragma unroll
        for (int p = 0; p < 3; ++p)
            acc = fmaf(po[p], W1[(6 + p) * LAT + j] - W1[p * LAT + j], acc);
        oc[o * LAT + j] = acc;
    } else {
        int o = row - N_Q - N_O;
        float acc = bv[j];
        #pragma unroll 8
        for (int k = 0; k < LAT; ++k)
            acc = fmaf(h_obs[o * LAT + k], Wv[k * LAT + j], acc);
        vv[o * LAT + j] = acc;
    }
}

// LDS layout (float words)
#define QCB 0        // qc tile [64][66] = 4224; region 4352 (aliased as acc[64][68])
#define OCB 4352     // 4 waves * 8 o * 64 = 2048
#define VVB 6400     // 2048
#define W2B 8448     // 64*4 (x log2e)
#define C9B 8704     // 64
#define LMB 8768     // 4*64*4
#define SMEM_WORDS 9792  // 39168 B

__global__ __launch_bounds__(256, 2) void attn_chunk(
    const float* __restrict__ pos_obs, const float* __restrict__ pos_query,
    const float* __restrict__ W1, const float* __restrict__ W2,
    const float* __restrict__ b2, const float* __restrict__ log_sigma,
    const float* __restrict__ qc, const float* __restrict__ oc,
    const float* __restrict__ vv, float* __restrict__ part)
{
    __shared__ float smem[SMEM_WORDS];

    const int chunk = blockIdx.x, qtile = blockIdx.y;
    const int tid = threadIdx.x;
    const int ql = tid & 63;
    const int og = __builtin_amdgcn_readfirstlane(tid >> 6);  // wave-uniform
    const int q = qtile * 64 + ql;

    const float sigma = __expf(log_sigma[0]) + 1e-6f;
    const float inv2s2l = L2E / (2.0f * sigma * sigma);
    const f2 b01 = (f2){b2[0] * L2E, b2[1] * L2E};
    const f2 b23 = (f2){b2[2] * L2E, b2[3] * L2E};

    // ---- block staging: qc tile [64][66], W2 (x log2e), c9 ----
    for (int idx = tid; idx < 1024; idx += 256) {
        int row = idx >> 4, c4 = idx & 15;
        float4 t = *(const float4*)(qc + ((size_t)(qtile * 64 + row)) * LAT + c4 * 4);
        int b = QCB + row * 66 + c4 * 4;
        smem[b] = t.x; smem[b + 1] = t.y; smem[b + 2] = t.z; smem[b + 3] = t.w;
    }
    if (tid < 64) {
        float4 t = *(const float4*)(W2 + tid * 4);
        float4 s; s.x = t.x * L2E; s.y = t.y * L2E; s.z = t.z * L2E; s.w = t.w * L2E;
        *(float4*)&smem[W2B + tid * 4] = s;
        smem[C9B + tid] = W1[9 * LAT + tid];
    }
    __syncthreads();

    const float qp0 = pos_query[q * 3 + 0];
    const float qp1 = pos_query[q * 3 + 1];
    const float qp2 = pos_query[q * 3 + 2];

    float m[HEADS], den[HEADS];
    f2 num2[HEADS][8];
    #pragma unroll
    for (int h = 0; h < HEADS; ++h) {
        m[h] = -1e30f; den[h] = 0.f;
        #pragma unroll
        for (int d = 0; d < 8; ++d) num2[h][d] = (f2)0.f;
    }

    const int obase = chunk * OCHUNK + og * 64;

    for (int r = 0; r < 8; ++r) {
        const int oslice = obase + r * 8;
        // wave-private restage of 8 o's of oc, vv (no barrier: private region)
        {
            const float4* osrc = (const float4*)(oc + (size_t)oslice * LAT);
            const float4* vsrc = (const float4*)(vv + (size_t)oslice * LAT);
            #pragma unroll
            for (int k = 0; k < 2; ++k) {
                *(float4*)&smem[OCB + og * 512 + (ql + 64 * k) * 4] = osrc[ql + 64 * k];
                *(float4*)&smem[VVB + og * 512 + (ql + 64 * k) * 4] = vsrc[ql + 64 * k];
            }
        }

        // distances + rbf (pos_obs addresses wave-uniform -> scalar loads)
        f2 rb2[8];
        f2 lg01[8], lg23[8];
        #pragma unroll
        for (int oi = 0; oi < 8; ++oi) {
            const float* po = pos_obs + (size_t)(oslice + oi) * 3;
            float r0 = qp0 - po[0], r1 = qp1 - po[1], r2 = qp2 - po[2];
            float d2 = fmaf(r0, r0, fmaf(r1, r1, r2 * r2));
            float rbf = __expf(-d2);
            rb2[oi] = (f2){rbf, rbf};
            float t = -d2 * inv2s2l;
            f2 ts = (f2){t, t};
            lg01[oi] = pk_add2(b01, ts);
            lg23[oi] = pk_add2(b23, ts);
        }

        // ---- hidden layer + W2, forced-packed: 4 j per j4 pass, 8 o's ----
        #pragma unroll 4
        for (int j4 = 0; j4 < 16; ++j4) {
            // wave-uniform operands (LDS broadcast reads)
            f4 w2r0 = *(const f4*)&smem[W2B + (j4 * 4 + 0) * 4];
            f4 w2r1 = *(const f4*)&smem[W2B + (j4 * 4 + 1) * 4];
            f4 w2r2 = *(const f4*)&smem[W2B + (j4 * 4 + 2) * 4];
            f4 w2r3 = *(const f4*)&smem[W2B + (j4 * 4 + 3) * 4];
            f4 c9v  = *(const f4*)&smem[C9B + j4 * 4];
            f2 c01 = c9v.xy, c23 = c9v.zw;
            f2 qv01 = *(const f2*)&smem[QCB + ql * 66 + j4 * 4];
            f2 qv23 = *(const f2*)&smem[QCB + ql * 66 + j4 * 4 + 2];

            #pragma unroll
            for (int oi = 0; oi < 8; ++oi) {
                f4 ocv = *(const f4*)&smem[OCB + og * 512 + oi * 64 + j4 * 4];
                // j-pair 0: j = 4*j4, 4*j4+1
                f2 t0 = pk_add2(qv01, ocv.xy);
                PK_FMA(t0, rb2[oi], c01);
                f2 hp0 = (f2){fmaxf(t0.x, 0.f), fmaxf(t0.y, 0.f)};
                PK_FMA_LO(lg01[oi], hp0, w2r0.xy);
                PK_FMA_LO(lg23[oi], hp0, w2r0.zw);
                PK_FMA_HI(lg01[oi], hp0, w2r1.xy);
                PK_FMA_HI(lg23[oi], hp0, w2r1.zw);
                // j-pair 1: j = 4*j4+2, 4*j4+3
                f2 t1 = pk_add2(qv23, ocv.zw);
                PK_FMA(t1, rb2[oi], c23);
                f2 hp1 = (f2){fmaxf(t1.x, 0.f), fmaxf(t1.y, 0.f)};
                PK_FMA_LO(lg01[oi], hp1, w2r2.xy);
                PK_FMA_LO(lg23[oi], hp1, w2r2.zw);
                PK_FMA_HI(lg01[oi], hp1, w2r3.xy);
                PK_FMA_HI(lg23[oi], hp1, w2r3.zw);
            }
        }

        // ---- online softmax + packed PV over the 8 o's ----
        #pragma unroll
        for (int oi = 0; oi < 8; ++oi) {
            const int vb = VVB + og * 512 + oi * 64;
            float l[HEADS] = {lg01[oi].x, lg01[oi].y, lg23[oi].x, lg23[oi].y};
            bool up = (l[0] > m[0]) || (l[1] > m[1]) || (l[2] > m[2]) || (l[3] > m[3]);
            if (!__any(up)) {
                #pragma unroll
                for (int h = 0; h < HEADS; ++h) {
                    float p = exp2f(l[h] - m[h]);
                    den[h] += p;
                    f2 p2 = (f2){p, p};
                    #pragma unroll
                    for (int d4 = 0; d4 < 4; ++d4) {
                        f4 t = *(const f4*)&smem[vb + h * HD + d4 * 4];
                        PK_FMA(num2[h][d4 * 2 + 0], p2, t.xy);
                        PK_FMA(num2[h][d4 * 2 + 1], p2, t.zw);
                    }
                }
            } else {
                #pragma unroll
                for (int h = 0; h < HEADS; ++h) {
                    float nm = fmaxf(m[h], l[h]);
                    float sc = exp2f(m[h] - nm);
                    float p  = exp2f(l[h] - nm);
                    m[h] = nm;
                    den[h] = fmaf(den[h], sc, p);
                    f2 p2 = (f2){p, p};
                    f2 sc2 = (f2){sc, sc};
                    #pragma unroll
                    for (int d4 = 0; d4 < 4; ++d4) {
                        f4 t = *(const f4*)&smem[vb + h * HD + d4 * 4];
                        PK_SCALE_FMA(num2[h][d4 * 2 + 0], sc2, p2, t.xy);
                        PK_SCALE_FMA(num2[h][d4 * 2 + 1], sc2, p2, t.zw);
                    }
                }
            }
        }
    }

    // ---- combine the 4 o-groups at the true chunk max ----
    #pragma unroll
    for (int h = 0; h < HEADS; ++h) smem[LMB + (og * 64 + ql) * 4 + h] = m[h];
    __syncthreads();
    #pragma unroll
    for (int h = 0; h < HEADS; ++h) {
        const float mc = fmaxf(
            fmaxf(smem[LMB + (0 * 64 + ql) * 4 + h], smem[LMB + (1 * 64 + ql) * 4 + h]),
            fmaxf(smem[LMB + (2 * 64 + ql) * 4 + h], smem[LMB + (3 * 64 + ql) * 4 + h]));
        const float sc = exp2f(m[h] - mc);
        den[h] *= sc;
        f2 sc2 = (f2){sc, sc};
        #pragma unroll
        for (int d = 0; d < 8; ++d) num2[h][d] = pk_mul2(num2[h][d], sc2);
    }
    __syncthreads();  // all qc reads done before aliasing acc region
    // staged accumulation into acc region (aliases qc region)
    for (int g = 0; g < 4; ++g) {
        if (og == g) {
            if (g == 0) {
                #pragma unroll
                for (int h = 0; h < HEADS; ++h) {
                    smem[QCB + ql * 68 + 64 + h] = den[h];
                    #pragma unroll
                    for (int d = 0; d < 8; ++d)
                        *(f2*)&smem[QCB + ql * 68 + h * HD + d * 2] = num2[h][d];
                }
            } else {
                #pragma unroll
                for (int h = 0; h < HEADS; ++h) {
                    smem[QCB + ql * 68 + 64 + h] += den[h];
                    #pragma unroll
                    for (int d = 0; d < 8; ++d) {
                        f2 cur = *(const f2*)&smem[QCB + ql * 68 + h * HD + d * 2];
                        *(f2*)&smem[QCB + ql * 68 + h * HD + d * 2] = cur + num2[h][d];
                    }
                }
            }
        }
        __syncthreads();
    }
    float* dst = part + (size_t)(chunk * N_Q + qtile * 64) * 68;
    for (int f = tid; f < 64 * 68; f += 256) {
        int qq = f / 68, e = f % 68;
        dst[(size_t)qq * 68 + e] = smem[QCB + qq * 68 + e];
    }
}

// ---- finalize: sum chunk partials, divide ----
__global__ __launch_bounds__(256) void finalize_k(
    const float* __restrict__ part, float* __restrict__ out)
{
    int gid = blockIdx.x * 256 + threadIdx.x;
    int q = gid >> 6, e = gid & 63;
    int h = e >> 4;
    float ns = 0.f, ds = 0.f;
    #pragma unroll
    for (int c = 0; c < NCHUNK; ++c) {
        const float* row = part + (size_t)(c * N_Q + q) * 68;
        ns += row[e];
        ds += row[64 + h];
    }
    out[q * LAT + e] = ns / (ds + 1e-9f);
}

extern "C" void kernel_launch(void* const* d_in, const int* in_sizes, int n_in,
                              void* d_out, int out_size, void* d_ws, size_t ws_size,
                              hipStream_t stream) {
    const float* h_obs     = (const float*)d_in[0];
    const float* pos_obs   = (const float*)d_in[1];
    const float* pos_query = (const float*)d_in[2];
    const float* W1        = (const float*)d_in[3];
    const float* b1        = (const float*)d_in[4];
    const float* W2        = (const float*)d_in[5];
    const float* b2        = (const float*)d_in[6];
    const float* Wv        = (const float*)d_in[7];
    const float* bv        = (const float*)d_in[8];
    const float* log_sigma = (const float*)d_in[9];
    float* out = (float*)d_out;

    float* w   = (float*)d_ws;
    float* qc  = w;                       // 4096*64
    float* oc  = qc + N_Q * LAT;          // 4096*64
    float* vv  = oc + (size_t)N_O * LAT;  // 4096*64
    float* part = vv + (size_t)N_O * LAT; // 16*4096*68

    prep_all<<<(N_Q + N_O + N_O) * LAT / 256, 256, 0, stream>>>(
        h_obs, pos_obs, pos_query, W1, b1, Wv, bv, qc, oc, vv);
    attn_chunk<<<dim3(NCHUNK, N_Q / 64), 256, 0, stream>>>(
        pos_obs, pos_query, W1, W2, b2, log_sigma, qc, oc, vv, part);
    finalize_k<<<N_Q * LAT / 256, 256, 0, stream>>>(part, out);
}

// Round 5
// 285.518 us; speedup vs baseline: 1.4105x; 1.4105x over previous
//
#include <hip/hip_runtime.h>

#define N_Q 4096
#define N_O 4096
#define LAT 64
#define NCHUNK 16
#define L2E 1.4426950408889634f
#define WAVES 4

typedef _Float16 h4 __attribute__((ext_vector_type(4)));
typedef _Float16 h8 __attribute__((ext_vector_type(8)));
typedef float f4v __attribute__((ext_vector_type(4)));

// ---- prep: v[o][hd] = h_obs[o]@Wv + bv ----
__global__ __launch_bounds__(256) void prep_v(
    const float* __restrict__ h_obs, const float* __restrict__ Wv,
    const float* __restrict__ bv, float* __restrict__ vv)
{
    int gid = blockIdx.x * 256 + threadIdx.x;
    int o = gid >> 6, j = gid & 63;
    float acc = bv[j];
    #pragma unroll 8
    for (int k = 0; k < LAT; ++k)
        acc = fmaf(h_obs[o * LAT + k], Wv[k * LAT + j], acc);
    vv[o * LAT + j] = acc;
}

// ---- main: per (chunk, 16-q tile) MFMA attention ----
// block = 4 waves, each wave owns one 16-q tile of the same chunk.
// Per o: stage1 swapped MFMA (feats@W1 -> hp, lane col=q), stage2 MFMA
// (hp@W2 + f32 dist term), deferred-max online softmax, PV MFMA (K=16,
// 8 o's + zero pad).
__global__ __launch_bounds__(256, 4) void attn_mfma(
    const float* __restrict__ pos_obs, const float* __restrict__ pos_query,
    const float* __restrict__ W1, const float* __restrict__ b1,
    const float* __restrict__ W2, const float* __restrict__ b2,
    const float* __restrict__ log_sigma,
    const float* __restrict__ vv, float* __restrict__ part)
{
    __shared__ __align__(16) _Float16 vt[4 * 16 * 72];        // [h][d][72o] quarter
    __shared__ __align__(16) float pos_lds[256][4];           // chunk o-positions
    __shared__ __align__(16) _Float16 es[WAVES][4][16][16];   // [h][q][o16] e-vals
    __shared__ __align__(16) float d2s[WAVES][8][16];         // [t][q] dist2
    __shared__ __align__(16) float scs[WAVES][4][16];         // [h][q] rescale

    const int tid = threadIdx.x;
    const int wv = tid >> 6, lane = tid & 63;
    const int col = lane & 15, g = lane >> 4;
    const int chunk = blockIdx.x & 15;
    const int qgroup = blockIdx.x >> 4;
    const int qbase = qgroup * 64 + wv * 16;

    const float sigma = __expf(log_sigma[0]) + 1e-6f;
    const float inv2s2l = L2E / (2.0f * sigma * sigma);
    const float b2lh = ((col < 4) ? b2[col] : b2[0]) * L2E;

    // ---- register fragments (built once; A/B pairing is element-consistent) ----
    // stage-1 A = W1^T padded to K=16: k-blocks g0:rel g1:qpos g2:opos g3:(rbf,1)
    h4 a1[4];
    #pragma unroll
    for (int jt = 0; jt < 4; ++jt) {
        int j = jt * 16 + col;
        #pragma unroll
        for (int e = 0; e < 4; ++e) {
            float v = 0.f;
            if (g < 3) { if (e < 3) v = W1[(g * 3 + e) * LAT + j]; }
            else { if (e == 0) v = W1[9 * LAT + j]; else if (e == 1) v = b1[j]; }
            a1[jt][e] = (_Float16)v;
        }
    }
    // stage-2 B = W2 (x log2e), j permuted to match the stage-1 C layout
    h8 b2f0, b2f1;
    #pragma unroll
    for (int e = 0; e < 8; ++e) {
        int j0 = ((e >> 2) + 0) * 16 + 4 * g + (e & 3);
        int j1 = ((e >> 2) + 2) * 16 + 4 * g + (e & 3);
        b2f0[e] = (_Float16)((col < 4) ? W2[j0 * 4 + col] * L2E : 0.f);
        b2f1[e] = (_Float16)((col < 4) ? W2[j1 * 4 + col] * L2E : 0.f);
    }
    // per-lane q position (q = qbase + col)
    const int q = qbase + col;
    const float qp0 = pos_query[q * 3 + 0];
    const float qp1 = pos_query[q * 3 + 1];
    const float qp2 = pos_query[q * 3 + 2];

    // ---- one-time LDS init ----
    {   // chunk o-positions
        int og = chunk * 256 + tid;
        pos_lds[tid][0] = pos_obs[og * 3 + 0];
        pos_lds[tid][1] = pos_obs[og * 3 + 1];
        pos_lds[tid][2] = pos_obs[og * 3 + 2];
        pos_lds[tid][3] = 0.f;
    }
    {   // zero es (incl. the o8..15 zero-pad used by PV A-frags)
        float* ez = (float*)&es[wv][0][0][0];
        for (int i = lane; i < 512; i += 64) ez[i] = 0.f;
    }
    {   // zero vt o-pad [64..72)
        for (int i = tid; i < 512; i += 256) vt[(i >> 3) * 72 + 64 + (i & 7)] = (_Float16)0.f;
    }

    float m_ref[4], tm[4], den[4];
    f4v cpv[4];
    #pragma unroll
    for (int rr = 0; rr < 4; ++rr) {
        m_ref[rr] = -1e30f; tm[rr] = -1e30f; den[rr] = 0.f;
        cpv[rr] = (f4v){0.f, 0.f, 0.f, 0.f};
    }
    __syncthreads();

    for (int qu = 0; qu < 4; ++qu) {
        __syncthreads();   // all waves done reading previous vt quarter
        // build vt quarter: [h][d][o_l] f16 from vv (coalesced reads)
        #pragma unroll
        for (int i = 0; i < 16; ++i) {
            int o_l = i * 4 + wv;
            float val = vv[((size_t)(chunk * 256 + qu * 64 + o_l)) * LAT + lane];
            vt[((lane >> 4) * 16 + (lane & 15)) * 72 + o_l] = (_Float16)val;
        }
        __syncthreads();

        for (int sb = 0; sb < 8; ++sb) {
            f4v lg[8];
            #pragma unroll
            for (int t = 0; t < 8; ++t) {
                const int oc = qu * 64 + sb * 8 + t;
                float4 pv = *(const float4*)&pos_lds[oc][0];
                float r0 = qp0 - pv.x, r1 = qp1 - pv.y, r2 = qp2 - pv.z;
                float d2 = fmaf(r0, r0, fmaf(r1, r1, r2 * r2));
                float rbf = __builtin_amdgcn_exp2f(-d2 * L2E);
                if (g == 3) d2s[wv][t][col] = d2;
                // B1 feats fragment (k-block by g)
                float v0 = (g == 0) ? r0 : (g == 1) ? qp0 : (g == 2) ? pv.x : rbf;
                float v1 = (g == 0) ? r1 : (g == 1) ? qp1 : (g == 2) ? pv.y : 1.0f;
                float v2 = (g == 0) ? r2 : (g == 1) ? qp2 : (g == 2) ? pv.z : 0.0f;
                h4 bf;
                bf[0] = (_Float16)v0; bf[1] = (_Float16)v1;
                bf[2] = (_Float16)v2; bf[3] = (_Float16)0.f;
                const f4v zc = (f4v){0.f, 0.f, 0.f, 0.f};
                f4v c10 = __builtin_amdgcn_mfma_f32_16x16x16f16(a1[0], bf, zc, 0, 0, 0);
                f4v c11 = __builtin_amdgcn_mfma_f32_16x16x16f16(a1[1], bf, zc, 0, 0, 0);
                f4v c12 = __builtin_amdgcn_mfma_f32_16x16x16f16(a1[2], bf, zc, 0, 0, 0);
                f4v c13 = __builtin_amdgcn_mfma_f32_16x16x16f16(a1[3], bf, zc, 0, 0, 0);
                // relu + cvt -> stage-2 A fragments
                h8 a2a, a2b;
                #pragma unroll
                for (int rr = 0; rr < 4; ++rr) {
                    a2a[rr]     = (_Float16)fmaxf(c10[rr], 0.f);
                    a2a[rr + 4] = (_Float16)fmaxf(c11[rr], 0.f);
                    a2b[rr]     = (_Float16)fmaxf(c12[rr], 0.f);
                    a2b[rr + 4] = (_Float16)fmaxf(c13[rr], 0.f);
                }
                // C-in: b2*log2e - d2*inv2s2*log2e (f32 path for the big term)
                float4 dv = *(const float4*)&d2s[wv][t][4 * g];
                f4v cin;
                cin[0] = fmaf(dv.x, -inv2s2l, b2lh);
                cin[1] = fmaf(dv.y, -inv2s2l, b2lh);
                cin[2] = fmaf(dv.z, -inv2s2l, b2lh);
                cin[3] = fmaf(dv.w, -inv2s2l, b2lh);
                f4v rs = __builtin_amdgcn_mfma_f32_16x16x32_f16(a2a, b2f0, cin, 0, 0, 0);
                lg[t]  = __builtin_amdgcn_mfma_f32_16x16x32_f16(a2b, b2f1, rs, 0, 0, 0);
            }

            // ---- deferred-max online softmax over the 8 o's ----
            float bm[4];
            bool upd = false;
            #pragma unroll
            for (int rr = 0; rr < 4; ++rr) {
                float b0 = fmaxf(fmaxf(lg[0][rr], lg[1][rr]), fmaxf(lg[2][rr], lg[3][rr]));
                float b1m = fmaxf(fmaxf(lg[4][rr], lg[5][rr]), fmaxf(lg[6][rr], lg[7][rr]));
                bm[rr] = fmaxf(b0, b1m);
                tm[rr] = fmaxf(tm[rr], bm[rr]);
                upd = upd || (bm[rr] > m_ref[rr] + 8.0f);
            }
            if (__any(upd)) {
                #pragma unroll
                for (int rr = 0; rr < 4; ++rr) {
                    float mn = fmaxf(m_ref[rr], bm[rr]);
                    float sc = __builtin_amdgcn_exp2f(m_ref[rr] - mn);
                    den[rr] *= sc;
                    if (col < 4) scs[wv][col][4 * g + rr] = sc;
                    m_ref[rr] = mn;
                }
                #pragma unroll
                for (int h = 0; h < 4; ++h) {
                    float4 s = *(const float4*)&scs[wv][h][4 * g];
                    cpv[h][0] *= s.x; cpv[h][1] *= s.y;
                    cpv[h][2] *= s.z; cpv[h][3] *= s.w;
                }
            }
            #pragma unroll
            for (int rr = 0; rr < 4; ++rr) {
                float er[8];
                #pragma unroll
                for (int t = 0; t < 8; ++t) {
                    er[t] = __builtin_amdgcn_exp2f(lg[t][rr] - m_ref[rr]);
                    den[rr] += er[t];
                }
                if (col < 4) {
                    h8 ev;
                    #pragma unroll
                    for (int t = 0; t < 8; ++t) ev[t] = (_Float16)er[t];
                    *(h8*)&es[wv][col][4 * g + rr][0] = ev;
                }
            }
            // ---- PV MFMA per head (K=16: 8 real o's + zero pad) ----
            #pragma unroll
            for (int h = 0; h < 4; ++h) {
                h4 ea = *(const h4*)&es[wv][h][col][4 * g];
                h4 vb = *(const h4*)&vt[(h * 16 + col) * 72 + sb * 8 + 4 * g];
                cpv[h] = __builtin_amdgcn_mfma_f32_16x16x16f16(ea, vb, cpv[h], 0, 0, 0);
            }
        }
    }

    // ---- final rescale to the true chunk max (reference semantics) ----
    #pragma unroll
    for (int rr = 0; rr < 4; ++rr) {
        float fsc = __builtin_amdgcn_exp2f(m_ref[rr] - tm[rr]);
        den[rr] *= fsc;
        if (col < 4) scs[wv][col][4 * g + rr] = fsc;
    }
    #pragma unroll
    for (int h = 0; h < 4; ++h) {
        float4 s = *(const float4*)&scs[wv][h][4 * g];
        cpv[h][0] *= s.x; cpv[h][1] *= s.y; cpv[h][2] *= s.z; cpv[h][3] *= s.w;
    }
    // ---- store partials: part[chunk][q][68] = {num[4][16], den[4]} ----
    #pragma unroll
    for (int h = 0; h < 4; ++h)
        #pragma unroll
        for (int rr = 0; rr < 4; ++rr) {
            size_t row = (size_t)(chunk * N_Q + qbase + 4 * g + rr);
            part[row * 68 + h * 16 + col] = cpv[h][rr];
        }
    if (col < 4) {
        #pragma unroll
        for (int rr = 0; rr < 4; ++rr) {
            size_t row = (size_t)(chunk * N_Q + qbase + 4 * g + rr);
            part[row * 68 + 64 + col] = den[rr];
        }
    }
}

// ---- finalize: sum chunk partials, divide ----
__global__ __launch_bounds__(256) void finalize_k(
    const float* __restrict__ part, float* __restrict__ out)
{
    int gid = blockIdx.x * 256 + threadIdx.x;
    int q = gid >> 6, e = gid & 63;
    int h = e >> 4;
    float ns = 0.f, ds = 0.f;
    #pragma unroll
    for (int c = 0; c < NCHUNK; ++c) {
        const float* row = part + (size_t)(c * N_Q + q) * 68;
        ns += row[e];
        ds += row[64 + h];
    }
    out[q * LAT + e] = ns / (ds + 1e-9f);
}

extern "C" void kernel_launch(void* const* d_in, const int* in_sizes, int n_in,
                              void* d_out, int out_size, void* d_ws, size_t ws_size,
                              hipStream_t stream) {
    const float* h_obs     = (const float*)d_in[0];
    const float* pos_obs   = (const float*)d_in[1];
    const float* pos_query = (const float*)d_in[2];
    const float* W1        = (const float*)d_in[3];
    const float* b1        = (const float*)d_in[4];
    const float* W2        = (const float*)d_in[5];
    const float* b2        = (const float*)d_in[6];
    const float* Wv        = (const float*)d_in[7];
    const float* bv        = (const float*)d_in[8];
    const float* log_sigma = (const float*)d_in[9];
    float* out = (float*)d_out;

    float* w    = (float*)d_ws;
    float* vv   = w;                        // 4096*64 f32
    float* part = vv + (size_t)N_O * LAT;   // 16*4096*68 f32

    prep_v<<<N_O * LAT / 256, 256, 0, stream>>>(h_obs, Wv, bv, vv);
    attn_mfma<<<NCHUNK * (N_Q / 64), 256, 0, stream>>>(
        pos_obs, pos_query, W1, b1, W2, b2, log_sigma, vv, part);
    finalize_k<<<N_Q * LAT / 256, 256, 0, stream>>>(part, out);
}

// Round 10
// 210.392 us; speedup vs baseline: 1.9142x; 1.3571x over previous
//
#include <hip/hip_runtime.h>

#define N_Q 4096
#define N_O 4096
#define LAT 64
#define NCHUNK 16
#define L2E 1.4426950408889634f
#define WAVES 4

typedef _Float16 h2 __attribute__((ext_vector_type(2)));
typedef _Float16 h4 __attribute__((ext_vector_type(4)));
typedef _Float16 h8 __attribute__((ext_vector_type(8)));
typedef float f4v __attribute__((ext_vector_type(4)));

// cvt_pkrtz returns __fp16x2; bit-cast to our _Float16x2
__device__ __forceinline__ h2 pkrtz(float a, float b) {
    return __builtin_bit_cast(h2, __builtin_amdgcn_cvt_pkrtz(a, b));
}
__device__ __forceinline__ h4 cat2(h2 a, h2 b) {
    return __builtin_shufflevector(a, b, 0, 1, 2, 3);
}
__device__ __forceinline__ h8 cat4(h4 a, h4 b) {
    return __builtin_shufflevector(a, b, 0, 1, 2, 3, 4, 5, 6, 7);
}
// packed relu(cvt(a), cvt(b)) : v_cvt_pkrtz_f16_f32 + v_pk_max_f16
__device__ __forceinline__ h2 relu_cvt(float a, float b) {
    h2 z = {(_Float16)0.f, (_Float16)0.f};
    return __builtin_elementwise_max(pkrtz(a, b), z);
}

// ---- prep: v[o][hd] = h_obs[o]@Wv + bv ----
__global__ __launch_bounds__(256) void prep_v(
    const float* __restrict__ h_obs, const float* __restrict__ Wv,
    const float* __restrict__ bv, float* __restrict__ vv)
{
    int gid = blockIdx.x * 256 + threadIdx.x;
    int o = gid >> 6, j = gid & 63;
    float acc = bv[j];
    #pragma unroll 8
    for (int k = 0; k < LAT; ++k)
        acc = fmaf(h_obs[o * LAT + k], Wv[k * LAT + j], acc);
    vv[o * LAT + j] = acc;
}

// ---- main: per (chunk, 16-q tile) MFMA attention ----
__global__ __launch_bounds__(256, 4) void attn_mfma(
    const float* __restrict__ pos_obs, const float* __restrict__ pos_query,
    const float* __restrict__ W1, const float* __restrict__ b1,
    const float* __restrict__ W2, const float* __restrict__ b2,
    const float* __restrict__ log_sigma,
    const float* __restrict__ vv, float* __restrict__ part)
{
    __shared__ __align__(16) _Float16 vt[64 * 76];   // row=(h*16+d) stride 76; o [0,64), zeros [64,76)
    __shared__ __align__(16) float pos_lds[256][4];
    __shared__ __align__(16) _Float16 es[WAVES][1096];  // wave-private: [q*68 + h*16 + o16]
    __shared__ __align__(16) float lgT[WAVES][8][16][4]; // wave-private: [t][q][h]
    __shared__ __align__(16) float d2s[WAVES][8][16];    // wave-private: [t][q]
    __shared__ __align__(16) float scs[WAVES][4][16];    // wave-private: [h][q]

    const int tid = threadIdx.x;
    const int wv = tid >> 6, lane = tid & 63;
    const int col = lane & 15, g = lane >> 4;
    const int qs = col, hs = g;                     // softmax ownership: lane = (q,h)
    const int chunk = blockIdx.x & 15;
    const int qgroup = blockIdx.x >> 4;
    const int qbase = qgroup * 64 + wv * 16;

    const float sigma = __expf(log_sigma[0]) + 1e-6f;
    const float inv2s2l = L2E / (2.0f * sigma * sigma);
    const float b2lh = ((col < 4) ? b2[col] : b2[0]) * L2E;

    // ---- stage-1 A = W1^T padded to K=16 (k-blocks g0:rel g1:qpos g2:opos g3:(rbf,b1)) ----
    h4 a1[4];
    #pragma unroll
    for (int jt = 0; jt < 4; ++jt) {
        int j = jt * 16 + col;
        #pragma unroll
        for (int e = 0; e < 4; ++e) {
            float v = 0.f;
            if (g < 3) { if (e < 3) v = W1[(g * 3 + e) * LAT + j]; }
            else { if (e == 0) v = W1[9 * LAT + j]; else if (e == 1) v = b1[j]; }
            a1[jt][e] = (_Float16)v;
        }
    }
    // ---- stage-2 B = W2 (x log2e), j permuted to match stage-1 C layout ----
    h8 b2f0, b2f1;
    #pragma unroll
    for (int e = 0; e < 8; ++e) {
        int j0 = ((e >> 2) + 0) * 16 + 4 * g + (e & 3);
        int j1 = ((e >> 2) + 2) * 16 + 4 * g + (e & 3);
        b2f0[e] = (_Float16)((col < 4) ? W2[j0 * 4 + col] * L2E : 0.f);
        b2f1[e] = (_Float16)((col < 4) ? W2[j1 * 4 + col] * L2E : 0.f);
    }
    const int q = qbase + col;
    const float qp0 = pos_query[q * 3 + 0];
    const float qp1 = pos_query[q * 3 + 1];
    const float qp2 = pos_query[q * 3 + 2];

    // ---- one-time LDS init ----
    {
        int og = chunk * 256 + tid;
        pos_lds[tid][0] = pos_obs[og * 3 + 0];
        pos_lds[tid][1] = pos_obs[og * 3 + 1];
        pos_lds[tid][2] = pos_obs[og * 3 + 2];
        pos_lds[tid][3] = 0.f;
    }
    {   // zero the wave's es region (incl. the o16 in [8,16) zero-pad)
        float* ez = (float*)&es[wv][0];
        for (int i = lane; i < 548; i += 64) ez[i] = 0.f;
    }
    // zero vt o-pad [64,76): 64 rows x 6 f32
    for (int i = tid; i < 384; i += 256)
        ((float*)vt)[(i / 6) * 38 + 32 + (i % 6)] = 0.f;

    float m_ref = -1e30f, tm = -1e30f, den = 0.f;
    f4v cpv[4];
    #pragma unroll
    for (int h = 0; h < 4; ++h) cpv[h] = (f4v){0.f, 0.f, 0.f, 0.f};
    __syncthreads();

    for (int qu = 0; qu < 4; ++qu) {
        __syncthreads();  // all waves done reading previous vt
        // ---- vt build: thread row = lane, o-range [wv*16, wv*16+16), b64 writes ----
        #pragma unroll
        for (int i = 0; i < 4; ++i) {
            int o0 = wv * 16 + i * 4;
            const float* vs = vv + (size_t)(chunk * 256 + qu * 64 + o0) * LAT + lane;
            *(h4*)&vt[lane * 76 + o0] =
                cat2(pkrtz(vs[0], vs[64]), pkrtz(vs[128], vs[192]));
        }
        __syncthreads();

        for (int sb = 0; sb < 8; ++sb) {
            // ---- per-o MLP (8 o's), logits straight to lgT transpose buffer ----
            #pragma unroll
            for (int t = 0; t < 8; ++t) {
                const int oc = qu * 64 + sb * 8 + t;
                float4 pv = *(const float4*)&pos_lds[oc][0];
                float r0 = qp0 - pv.x, r1 = qp1 - pv.y, r2 = qp2 - pv.z;
                float d2 = fmaf(r0, r0, fmaf(r1, r1, r2 * r2));
                float rbf = __builtin_amdgcn_exp2f(-d2 * L2E);
                if (g == 3) d2s[wv][t][col] = d2;
                float v0 = (g == 0) ? r0 : (g == 1) ? qp0 : (g == 2) ? pv.x : rbf;
                float v1 = (g == 0) ? r1 : (g == 1) ? qp1 : (g == 2) ? pv.y : 1.0f;
                float v2 = (g == 0) ? r2 : (g == 1) ? qp2 : (g == 2) ? pv.z : 0.0f;
                h4 bf = cat2(pkrtz(v0, v1), pkrtz(v2, 0.f));
                const f4v zc = (f4v){0.f, 0.f, 0.f, 0.f};
                f4v c10 = __builtin_amdgcn_mfma_f32_16x16x16f16(a1[0], bf, zc, 0, 0, 0);
                f4v c11 = __builtin_amdgcn_mfma_f32_16x16x16f16(a1[1], bf, zc, 0, 0, 0);
                f4v c12 = __builtin_amdgcn_mfma_f32_16x16x16f16(a1[2], bf, zc, 0, 0, 0);
                f4v c13 = __builtin_amdgcn_mfma_f32_16x16x16f16(a1[3], bf, zc, 0, 0, 0);
                h8 a2a = cat4(cat2(relu_cvt(c10[0], c10[1]), relu_cvt(c10[2], c10[3])),
                              cat2(relu_cvt(c11[0], c11[1]), relu_cvt(c11[2], c11[3])));
                h8 a2b = cat4(cat2(relu_cvt(c12[0], c12[1]), relu_cvt(c12[2], c12[3])),
                              cat2(relu_cvt(c13[0], c13[1]), relu_cvt(c13[2], c13[3])));
                f4v dv = *(const f4v*)&d2s[wv][t][4 * g];
                f4v cin;
                cin[0] = fmaf(dv[0], -inv2s2l, b2lh);
                cin[1] = fmaf(dv[1], -inv2s2l, b2lh);
                cin[2] = fmaf(dv[2], -inv2s2l, b2lh);
                cin[3] = fmaf(dv[3], -inv2s2l, b2lh);
                f4v rs  = __builtin_amdgcn_mfma_f32_16x16x32_f16(a2a, b2f0, cin, 0, 0, 0);
                f4v lgv = __builtin_amdgcn_mfma_f32_16x16x32_f16(a2b, b2f1, rs, 0, 0, 0);
                if (col < 4) {   // only h<4 columns are real
                    lgT[wv][t][4 * g + 0][col] = lgv[0];
                    lgT[wv][t][4 * g + 1][col] = lgv[1];
                    lgT[wv][t][4 * g + 2][col] = lgv[2];
                    lgT[wv][t][4 * g + 3][col] = lgv[3];
                }
            }

            // ---- softmax: each lane owns one (q,h); 8 exps only ----
            float er[8];
            #pragma unroll
            for (int t = 0; t < 8; ++t) er[t] = lgT[wv][t][qs][hs];
            float bm = fmaxf(fmaxf(fmaxf(er[0], er[1]), fmaxf(er[2], er[3])),
                             fmaxf(fmaxf(er[4], er[5]), fmaxf(er[6], er[7])));
            tm = fmaxf(tm, bm);
            if (__any(bm > m_ref + 8.0f)) {       // deferred-max rescale (rare)
                float mn = fmaxf(m_ref, bm);
                float sc = __builtin_amdgcn_exp2f(m_ref - mn);
                den *= sc; m_ref = mn;
                scs[wv][hs][qs] = sc;
                #pragma unroll
                for (int h = 0; h < 4; ++h) {
                    f4v s = *(const f4v*)&scs[wv][h][4 * g];
                    cpv[h] *= s;
                }
            }
            #pragma unroll
            for (int t = 0; t < 8; ++t) {
                er[t] = __builtin_amdgcn_exp2f(er[t] - m_ref);
                den += er[t];
            }
            *(h4*)&es[wv][qs * 68 + hs * 16 + 0] =
                cat2(pkrtz(er[0], er[1]), pkrtz(er[2], er[3]));
            *(h4*)&es[wv][qs * 68 + hs * 16 + 4] =
                cat2(pkrtz(er[4], er[5]), pkrtz(er[6], er[7]));

            // ---- PV MFMA per head (K=16: 8 real + 8 zero-pad) ----
            #pragma unroll
            for (int h = 0; h < 4; ++h) {
                h4 ea = *(const h4*)&es[wv][col * 68 + h * 16 + 4 * g];
                h4 vb = *(const h4*)&vt[(h * 16 + col) * 76 + sb * 8 + 4 * g];
                cpv[h] = __builtin_amdgcn_mfma_f32_16x16x16f16(ea, vb, cpv[h], 0, 0, 0);
            }
        }
    }

    // ---- final rescale to the true chunk max (reference semantics) ----
    {
        float fsc = __builtin_amdgcn_exp2f(m_ref - tm);
        den *= fsc;
        scs[wv][hs][qs] = fsc;
        #pragma unroll
        for (int h = 0; h < 4; ++h) {
            f4v s = *(const f4v*)&scs[wv][h][4 * g];
            cpv[h] *= s;
        }
    }
    // ---- store partials: part[chunk][q][68] = {num[4][16], den[4]} ----
    #pragma unroll
    for (int h = 0; h < 4; ++h)
        #pragma unroll
        for (int rr = 0; rr < 4; ++rr)
            part[(size_t)(chunk * N_Q + qbase + 4 * g + rr) * 68 + h * 16 + col] = cpv[h][rr];
    part[(size_t)(chunk * N_Q + qbase + qs) * 68 + 64 + hs] = den;
}

// ---- finalize: sum chunk partials, divide ----
__global__ __launch_bounds__(256) void finalize_k(
    const float* __restrict__ part, float* __restrict__ out)
{
    int gid = blockIdx.x * 256 + threadIdx.x;
    int q = gid >> 6, e = gid & 63;
    int h = e >> 4;
    float ns = 0.f, ds = 0.f;
    #pragma unroll
    for (int c = 0; c < NCHUNK; ++c) {
        const float* row = part + (size_t)(c * N_Q + q) * 68;
        ns += row[e];
        ds += row[64 + h];
    }
    out[q * LAT + e] = ns / (ds + 1e-9f);
}

extern "C" void kernel_launch(void* const* d_in, const int* in_sizes, int n_in,
                              void* d_out, int out_size, void* d_ws, size_t ws_size,
                              hipStream_t stream) {
    const float* h_obs     = (const float*)d_in[0];
    const float* pos_obs   = (const float*)d_in[1];
    const float* pos_query = (const float*)d_in[2];
    const float* W1        = (const float*)d_in[3];
    const float* b1        = (const float*)d_in[4];
    const float* W2        = (const float*)d_in[5];
    const float* b2        = (const float*)d_in[6];
    const float* Wv        = (const float*)d_in[7];
    const float* bv        = (const float*)d_in[8];
    const float* log_sigma = (const float*)d_in[9];
    float* out = (float*)d_out;

    float* w    = (float*)d_ws;
    float* vv   = w;                        // 4096*64 f32
    float* part = vv + (size_t)N_O * LAT;   // 16*4096*68 f32

    prep_v<<<N_O * LAT / 256, 256, 0, stream>>>(h_obs, Wv, bv, vv);
    attn_mfma<<<NCHUNK * (N_Q / 64), 256, 0, stream>>>(
        pos_obs, pos_query, W1, b1, W2, b2, log_sigma, vv, part);
    finalize_k<<<N_Q * LAT / 256, 256, 0, stream>>>(part, out);
}